// Round 17
// baseline (225.337 us; speedup 1.0000x reference)
//
#include <hip/hip_runtime.h>

typedef _Float16 half4  __attribute__((ext_vector_type(4)));
typedef _Float16 half8  __attribute__((ext_vector_type(8)));
typedef float    f32x4  __attribute__((ext_vector_type(4)));

#define EC 768   // per-wave LDS edge-index capacity for layer-1 chain-break

// ---------------- count + weight prep (all CSR-independent work) -------------------
// B-frag order: lane holds B[kt*32+(lane>>4)*8+j][nt*16+(lane&15)], j=0..7.
__device__ __forceinline__ void pack_dev(const float* Wa, const float* Wb,
                                         _Float16* out, int NT, int ncols, int t) {
  int lane = t & 63, tile = t >> 6;
  int nt = tile % NT, kt = tile / NT;
  int n  = nt * 16 + (lane & 15);
  int kb = kt * 32 + (lane >> 4) * 8;
  half8 o;
#pragma unroll
  for (int j = 0; j < 8; ++j) {
    int k = kb + j;
    float w = (k < 128) ? Wa[k * ncols + n] : Wb[(k - 128) * ncols + n];
    o[j] = (_Float16)w;
  }
  *(half8*)(out + (long)t * 8) = o;
}

__global__ void count_k(const int* __restrict__ dst, int* __restrict__ deg,
                        const float* __restrict__ W1l, const float* __restrict__ W1r,
                        _Float16* __restrict__ Wp1,
                        const float* __restrict__ W2l, const float* __restrict__ W2r,
                        const float* __restrict__ Wc,  _Float16* __restrict__ Wz,
                        const float* __restrict__ b2,  const float* __restrict__ bc,
                        float* __restrict__ bprime, int E, int FB) {
  int b = blockIdx.x;
  if (b < FB) {                                    // degree count
    int t = b * 256 + threadIdx.x;
    if (t < E) atomicAdd(&deg[dst[t]], 1);
  } else if (b < FB + 16) {                        // W1 concat pack (KT=8, NT=8)
    pack_dev(W1l, W1r, Wp1, 8, 128, (b - FB) * 256 + threadIdx.x);
  } else if (b < FB + 32) {                        // Wz fold: one elem/thread
    int i = (b - FB - 16) * 256 + threadIdx.x;     // packed element index, 4096 total
    int j = i & 7, lane = (i >> 3) & 63, tile = i >> 9;
    int nt = tile & 1, kt = tile >> 1;
    int k = kt * 32 + (lane >> 4) * 8 + j;
    int c = lane & 15;
    const float* W = nt ? W2r : W2l;
    float s = 0.f;
#pragma unroll 8
    for (int q = 0; q < 128; ++q) s += W[k * 128 + q] * Wc[q * 16 + c];
    Wz[i] = (_Float16)s;
  } else {                                         // b' = b2@Wc + bc
    int n = threadIdx.x;
    if (n < 16) {
      float s = bc[n];
      for (int k = 0; k < 128; ++k) s += b2[k] * Wc[k * 16 + n];
      bprime[n] = s;
    }
  }
}

// ---------------- single-dispatch scan: row_off from deg --------------------------
// Block b: chunk offset = coalesced sum of deg[0..b*256) (L2-hot, ~b iters/thread),
// then LDS-scan its own 256-chunk. Replaces deg_part + row_off (one fewer dispatch).
__global__ void scan_k(const int* __restrict__ deg, int* __restrict__ row_off,
                       int N, int NB) {
  __shared__ int red[256];
  __shared__ int sm[256];
  int b = blockIdx.x, tl = threadIdx.x;
  int s = 0, lim = b * 256;
  for (int i = tl; i < lim; i += 256) s += deg[i];
  red[tl] = s; __syncthreads();
  for (int off = 128; off > 0; off >>= 1) {
    if (tl < off) red[tl] += red[tl + off];
    __syncthreads();
  }
  int chunk_off = red[0];
  int t = b * 256 + tl;
  int v = (t < N) ? deg[t] : 0;
  sm[tl] = v; __syncthreads();
  for (int off = 1; off < 256; off <<= 1) {
    int a = sm[tl]; int x = (tl >= off) ? sm[tl - off] : 0;
    __syncthreads(); sm[tl] = a + x; __syncthreads();
  }
  if (t < N) row_off[t] = chunk_off + sm[tl] - v;
  if (b == NB - 1 && tl == 255) row_off[N] = chunk_off + sm[255];
}

// ---------------- post: INTERLEAVED CSR fill + emb gather -------------------------
// Fill (atomic+scatter-write-bound) and gather (random-read-bound) blocks alternate
// in a 3:4 period so both are co-resident machine-wide instead of phase-sequential.
__global__ void post_k(const int* __restrict__ src, const int* __restrict__ dst,
                       const int* __restrict__ row_off, int* __restrict__ cur,
                       int* __restrict__ csr,
                       const int* __restrict__ ent, const float* __restrict__ emb,
                       _Float16* __restrict__ X,
                       int N, int E, int FB, int GB) {
  int b = blockIdx.x;
  int per = b / 7, ph = b % 7;
  if (ph < 3) {                                    // fill role (3 per period)
    int fb = per * 3 + ph;
    if (fb >= FB) return;
    int t = fb * 256 + threadIdx.x;
    if (t < E) {
      int d = dst[t];
      int p = atomicAdd(&cur[d], 1);
      csr[row_off[d] + p] = src[t];
    }
  } else {                                         // gather role (4 per period)
    int gb = per * 4 + (ph - 3);
    if (gb >= GB) return;
    int t = gb * 256 + threadIdx.x;
    if (t >= N * 16) return;
    int node = t >> 4, g = t & 15;
    const float4* s = (const float4*)(emb + (long)ent[node] * 128 + g * 8);
    float4 a = s[0], c = s[1];
    half8 o;
    o[0] = (_Float16)a.x; o[1] = (_Float16)a.y; o[2] = (_Float16)a.z; o[3] = (_Float16)a.w;
    o[4] = (_Float16)c.x; o[5] = (_Float16)c.y; o[6] = (_Float16)c.z; o[7] = (_Float16)c.w;
    *(half8*)(X + (long)t * 8) = o;
  }
}

// ---------------- layer-1 gather+mean into LDS tile (16 rows x 128, stride 136) ----
// Chain-broken: stage tile's contiguous CSR slice into LDS, then X-loads from LDS idx.
__device__ __forceinline__ void agg_to_lds(const _Float16* __restrict__ X,
                                           const int* __restrict__ row_off,
                                           const int* __restrict__ csr,
                                           _Float16* ab, int* eidx,
                                           int row0, int M, int lane) {
  int nd_end = min(row0 + 16, M);
  int ebeg = row_off[row0 < M ? row0 : M - 1];
  int eend = row_off[nd_end];
  int cnt  = eend - ebeg;
  bool fits = (cnt <= EC);
  if (fits)
    for (int i = lane; i < cnt; i += 64) eidx[i] = csr[ebeg + i];
  int g = lane >> 4, j = lane & 15;
#pragma unroll
  for (int batch = 0; batch < 4; ++batch) {
    int node = row0 + batch * 4 + g;
    int nc = (node < M) ? node : M - 1;
    int beg = row_off[nc], end = row_off[nc + 1];
    half8 acc = (half8)(_Float16)0.f;
    if (fits) {
      const int* ix = eidx + (beg - ebeg);
      int n = end - beg;
#pragma unroll 8
      for (int e = 0; e < n; ++e) {
        half8 v = *(const half8*)(X + (long)ix[e] * 128 + j * 8);
        acc += v;
      }
    } else {
#pragma unroll 8
      for (int e = beg; e < end; ++e) {
        half8 v = *(const half8*)(X + (long)csr[e] * 128 + j * 8);
        acc += v;
      }
    }
    _Float16 inv = (_Float16)(1.f / fmaxf((float)(end - beg), 1.f));
    acc *= (half8)inv;
    *(half8*)(ab + (batch * 4 + g) * 136 + j * 8) = acc;
  }
}

// ---------------- fused layer-1 + folded layer-2 GEMM ------------------------------
// h1 tile never touches global: agg -> K=256 MFMA vs Wp1 -> +b1,relu -> stage into the
// (now dead) ab LDS tile -> 8 MFMAs vs Bz -> Zl (f16) + Pr (f32). Wave-private, no barrier.
__global__ __launch_bounds__(128) void gemm1z_k(const _Float16* __restrict__ X,
                                                const int* __restrict__ row_off,
                                                const int* __restrict__ csr,
                                                const _Float16* __restrict__ Bp,
                                                const float* __restrict__ bias,
                                                const _Float16* __restrict__ Bz,
                                                const float* __restrict__ bprime,
                                                _Float16* __restrict__ Zl,
                                                float* __restrict__ Pr, int M) {
  __shared__ _Float16 abuf[2][16 * 136];
  __shared__ int      ebuf[2][EC];
  int wave = threadIdx.x >> 6, lane = threadIdx.x & 63;
  _Float16* ab = abuf[wave];
  int row0 = blockIdx.x * 32 + wave * 16;
  agg_to_lds(X, row_off, csr, ab, ebuf[wave], row0, M, lane);
  int m = lane & 15, quad = lane >> 4;
  int arow = row0 + m; if (arow > M - 1) arow = M - 1;
  f32x4 acc[8];
#pragma unroll
  for (int i = 0; i < 8; ++i) acc[i] = (f32x4){0.f, 0.f, 0.f, 0.f};
#pragma unroll
  for (int kt = 0; kt < 8; ++kt) {
    half8 af = (kt < 4) ? *(const half8*)(ab + m * 136 + kt * 32 + quad * 8)
                        : *(const half8*)(X + (long)arow * 128 + (kt - 4) * 32 + quad * 8);
#pragma unroll
    for (int nt = 0; nt < 8; ++nt) {
      half8 bf = *(const half8*)(Bp + ((long)(kt * 8 + nt) * 64 + lane) * 8);
      acc[nt] = __builtin_amdgcn_mfma_f32_16x16x32_f16(af, bf, acc[nt], 0, 0, 0);
    }
  }
  // h1 tile: +b1, relu, stage into ab (agg contents are dead; same f16 rounding as
  // the old global h1 path -> bit-identical). K-loop LDS reads complete in-order.
#pragma unroll
  for (int nt = 0; nt < 8; ++nt) {
    float bv = bias[nt * 16 + m];
#pragma unroll
    for (int r = 0; r < 4; ++r)
      ab[(quad * 4 + r) * 136 + nt * 16 + m] = (_Float16)fmaxf(acc[nt][r] + bv, 0.f);
  }
  // folded layer-2: Zl = h1@W2lc, Pr = h1@W2rc + b'
  f32x4 a0 = (f32x4){0.f, 0.f, 0.f, 0.f}, a1 = a0;
#pragma unroll
  for (int kt = 0; kt < 4; ++kt) {
    half8 af = *(const half8*)(ab + m * 136 + kt * 32 + quad * 8);
    half8 b0 = *(const half8*)(Bz + ((long)(kt * 2 + 0) * 64 + lane) * 8);
    half8 b1 = *(const half8*)(Bz + ((long)(kt * 2 + 1) * 64 + lane) * 8);
    a0 = __builtin_amdgcn_mfma_f32_16x16x32_f16(af, b0, a0, 0, 0, 0);
    a1 = __builtin_amdgcn_mfma_f32_16x16x32_f16(af, b1, a1, 0, 0, 0);
  }
  float bv = bprime[m];
#pragma unroll
  for (int r = 0; r < 4; ++r) {
    int orow = row0 + quad * 4 + r;
    if (orow < M) {
      Zl[(long)orow * 16 + m] = (_Float16)a0[r];
      Pr[(long)orow * 16 + m] = a1[r] + bv;
    }
  }
}

// ---------------- final: out = mean_agg(Zl) + Pr --------------------------------
__global__ __launch_bounds__(256) void aggout_k(const _Float16* __restrict__ Zl,
                                                const float* __restrict__ Pr,
                                                const int* __restrict__ row_off,
                                                const int* __restrict__ csr,
                                                float* __restrict__ out, int M) {
  int t = blockIdx.x * 256 + threadIdx.x;
  int node = t >> 2, q = t & 3;
  if (node >= M) return;
  int beg = row_off[node], end = row_off[node + 1];
  float a0 = 0.f, a1 = 0.f, a2 = 0.f, a3 = 0.f;
#pragma unroll 8
  for (int e = beg; e < end; ++e) {
    half4 v = *(const half4*)(Zl + (long)csr[e] * 16 + q * 4);
    a0 += (float)v[0]; a1 += (float)v[1]; a2 += (float)v[2]; a3 += (float)v[3];
  }
  float inv = 1.f / fmaxf((float)(end - beg), 1.f);
  long o = (long)node * 16 + q * 4;
  const float4 pv = *(const float4*)(Pr + o);
  float4 ov;
  ov.x = a0 * inv + pv.x; ov.y = a1 * inv + pv.y;
  ov.z = a2 * inv + pv.z; ov.w = a3 * inv + pv.w;
  *(float4*)(out + o) = ov;
}

extern "C" void kernel_launch(void* const* d_in, const int* in_sizes, int n_in,
                              void* d_out, int out_size, void* d_ws, size_t ws_size,
                              hipStream_t stream) {
  const int N = in_sizes[0];
  const int E = in_sizes[1] / 2;
  const int*   entity = (const int*)d_in[0];
  const int*   e_src  = (const int*)d_in[1];
  const int*   e_dst  = e_src + E;
  const float* emb    = (const float*)d_in[2];
  const float* W1l    = (const float*)d_in[3];
  const float* b1     = (const float*)d_in[4];
  const float* W1r    = (const float*)d_in[5];
  const float* W2l    = (const float*)d_in[6];
  const float* b2     = (const float*)d_in[7];
  const float* W2r    = (const float*)d_in[8];
  const float* Wc     = (const float*)d_in[9];
  const float* bc     = (const float*)d_in[10];
  float* out = (float*)d_out;

  // workspace layout
  char* p = (char*)d_ws;
  _Float16* x0  = (_Float16*)p; p += (size_t)N * 128 * 2;
  _Float16* Wp1 = (_Float16*)p; p += 256 * 128 * 2;
  _Float16* Wz  = (_Float16*)p; p += 128 * 32 * 2;
  float*    bpr = (float*)p;    p += 16 * 4;
  _Float16* Zl  = (_Float16*)p; p += (size_t)N * 16 * 2;
  float*    Pr  = (float*)p;    p += (size_t)N * 16 * 4;
  int* deg     = (int*)p; p += (size_t)N * 4;
  int* cur     = (int*)p; p += (size_t)N * 4;               // adjacent to deg: one memset
  int* row_off = (int*)p; p += (size_t)(N + 1) * 4;
  int* csr     = (int*)p; p += (size_t)E * 4;

  const int NB = (N + 255) / 256;          // 196
  const int FB = (E + 255) / 256;          // 2344 fill blocks
  const int GB = (N * 16 + 255) / 256;     // 3125 gather blocks
  const int PER = (FB + 2) / 3 > (GB + 3) / 4 ? (FB + 2) / 3 : (GB + 3) / 4;  // 782
  const int IB = PER * 7;                  // interleaved region size

  hipMemsetAsync(deg, 0, (size_t)N * 8, stream);            // zeros deg + cur

  // count + all weight prep (CSR-independent)
  count_k<<<FB + 33, 256, 0, stream>>>(e_dst, deg, W1l, W1r, Wp1,
                                       W2l, W2r, Wc, Wz, b2, bc, bpr, E, FB);
  // single-dispatch scan: deg -> row_off
  scan_k<<<NB, 256, 0, stream>>>(deg, row_off, N, NB);
  // interleaved CSR fill + emb gather
  post_k<<<IB, 256, 0, stream>>>(e_src, e_dst, row_off, cur, csr,
                                 entity, emb, x0, N, E, FB, GB);
  // fused: h1 = relu([mean_agg(x0)|x0]@Wp1+b1) -> Zl = h1@W2lc, Pr = h1@W2rc + b'
  gemm1z_k<<<(N + 31) / 32, 128, 0, stream>>>(x0, row_off, csr, Wp1, b1,
                                              Wz, bpr, Zl, Pr, N);
  // out = mean_agg(Zl) + Pr   (32 B/edge gather)
  aggout_k<<<(N * 4 + 255) / 256, 256, 0, stream>>>(Zl, Pr, row_off, csr, out, N);
}

// Round 18
// 198.599 us; speedup vs baseline: 1.1346x; 1.1346x over previous
//
#include <hip/hip_runtime.h>

typedef _Float16 half4  __attribute__((ext_vector_type(4)));
typedef _Float16 half8  __attribute__((ext_vector_type(8)));
typedef float    f32x4  __attribute__((ext_vector_type(4)));

#define EC 768   // per-wave LDS edge-index capacity for layer-1 chain-break

// ---------------- degree count (standalone: the only input the scan needs) --------
__global__ void count_k(const int* __restrict__ dst, int* __restrict__ deg, int E) {
  int t = blockIdx.x * 256 + threadIdx.x;
  if (t < E) atomicAdd(&deg[dst[t]], 1);
}

__global__ void deg_part_k(const int* __restrict__ deg, int* __restrict__ part, int N) {
  int t = blockIdx.x * 256 + threadIdx.x;
  int v = (t < N) ? deg[t] : 0;
  v += __shfl_down(v, 32); v += __shfl_down(v, 16); v += __shfl_down(v, 8);
  v += __shfl_down(v, 4);  v += __shfl_down(v, 2);  v += __shfl_down(v, 1);
  __shared__ int sm[4];
  if ((threadIdx.x & 63) == 0) sm[threadIdx.x >> 6] = v;
  __syncthreads();
  if (threadIdx.x == 0) part[blockIdx.x] = sm[0] + sm[1] + sm[2] + sm[3];
}

__global__ void row_off_k(const int* __restrict__ deg, const int* __restrict__ part,
                          int* __restrict__ row_off, int N, int NB) {
  __shared__ int ps[256];
  __shared__ int sm[256];
  int tl = threadIdx.x;
  int pv = (tl < NB) ? part[tl] : 0;
  ps[tl] = pv; __syncthreads();
  for (int off = 1; off < 256; off <<= 1) {
    int a = ps[tl]; int b = (tl >= off) ? ps[tl - off] : 0;
    __syncthreads(); ps[tl] = a + b; __syncthreads();
  }
  int chunk_off = (blockIdx.x > 0) ? ps[blockIdx.x - 1] : 0;
  if (blockIdx.x == 0 && tl == 255) row_off[N] = ps[255];
  int t = blockIdx.x * 256 + tl;
  int v = (t < N) ? deg[t] : 0;
  sm[tl] = v; __syncthreads();
  for (int off = 1; off < 256; off <<= 1) {
    int a = sm[tl]; int b = (tl >= off) ? sm[tl - off] : 0;
    __syncthreads(); sm[tl] = a + b; __syncthreads();
  }
  if (t < N) row_off[t] = chunk_off + sm[tl] - v;
}

// ---------------- post: INTERLEAVED CSR fill + emb gather (+ packs at tail) --------
// Fill (atomic+scatter-write-bound) and gather (random-read-bound) blocks alternate
// in a 3:4 period so both are co-resident machine-wide instead of phase-sequential.
// B-frag order: lane holds B[kt*32+(lane>>4)*8+j][nt*16+(lane&15)], j=0..7.
__device__ __forceinline__ void pack_dev(const float* Wa, const float* Wb,
                                         _Float16* out, int NT, int ncols, int t) {
  int lane = t & 63, tile = t >> 6;
  int nt = tile % NT, kt = tile / NT;
  int n  = nt * 16 + (lane & 15);
  int kb = kt * 32 + (lane >> 4) * 8;
  half8 o;
#pragma unroll
  for (int j = 0; j < 8; ++j) {
    int k = kb + j;
    float w = (k < 128) ? Wa[k * ncols + n] : Wb[(k - 128) * ncols + n];
    o[j] = (_Float16)w;
  }
  *(half8*)(out + (long)t * 8) = o;
}

__global__ void post_k(const int* __restrict__ src, const int* __restrict__ dst,
                       const int* __restrict__ row_off, int* __restrict__ cur,
                       int* __restrict__ csr,
                       const int* __restrict__ ent, const float* __restrict__ emb,
                       _Float16* __restrict__ X,
                       const float* __restrict__ W1l, const float* __restrict__ W1r, _Float16* __restrict__ Wp1,
                       const float* __restrict__ W2l, const float* __restrict__ W2r,
                       const float* __restrict__ Wc,  _Float16* __restrict__ Wz,
                       const float* __restrict__ b2,  const float* __restrict__ bc,
                       float* __restrict__ bprime,
                       int N, int E, int FB, int GB, int IB) {
  int b = blockIdx.x;
  if (b < IB) {                                    // interleaved fill/gather region
    int per = b / 7, ph = b % 7;
    if (ph < 3) {                                  // fill role (3 per period)
      int fb = per * 3 + ph;
      if (fb >= FB) return;
      int t = fb * 256 + threadIdx.x;
      if (t < E) {
        int d = dst[t];
        int p = atomicAdd(&cur[d], 1);
        csr[row_off[d] + p] = src[t];
      }
    } else {                                       // gather role (4 per period)
      int gb = per * 4 + (ph - 3);
      if (gb >= GB) return;
      int t = gb * 256 + threadIdx.x;
      if (t >= N * 16) return;
      int node = t >> 4, g = t & 15;
      const float4* s = (const float4*)(emb + (long)ent[node] * 128 + g * 8);
      float4 a = s[0], c = s[1];
      half8 o;
      o[0] = (_Float16)a.x; o[1] = (_Float16)a.y; o[2] = (_Float16)a.z; o[3] = (_Float16)a.w;
      o[4] = (_Float16)c.x; o[5] = (_Float16)c.y; o[6] = (_Float16)c.z; o[7] = (_Float16)c.w;
      *(half8*)(X + (long)t * 8) = o;
    }
  } else if (b < IB + 16) {                        // W1 concat pack (KT=8, NT=8)
    pack_dev(W1l, W1r, Wp1, 8, 128, (b - IB) * 256 + threadIdx.x);
  } else if (b < IB + 32) {                        // Wz fold: one elem/thread, 16 blocks
    int i = (b - IB - 16) * 256 + threadIdx.x;     // packed element index, 4096 total
    int j = i & 7, lane = (i >> 3) & 63, tile = i >> 9;
    int nt = tile & 1, kt = tile >> 1;
    int k = kt * 32 + (lane >> 4) * 8 + j;
    int c = lane & 15;
    const float* W = nt ? W2r : W2l;
    float s = 0.f;
#pragma unroll 8
    for (int q = 0; q < 128; ++q) s += W[k * 128 + q] * Wc[q * 16 + c];
    Wz[i] = (_Float16)s;
  } else {                                         // b' = b2@Wc + bc
    int n = threadIdx.x;
    if (n < 16) {
      float s = bc[n];
      for (int k = 0; k < 128; ++k) s += b2[k] * Wc[k * 16 + n];
      bprime[n] = s;
    }
  }
}

// ---------------- layer-1 gather+mean into LDS tile (16 rows x 128, stride 136) ----
// Chain-broken: stage tile's contiguous CSR slice into LDS, then X-loads from LDS idx.
__device__ __forceinline__ void agg_to_lds(const _Float16* __restrict__ X,
                                           const int* __restrict__ row_off,
                                           const int* __restrict__ csr,
                                           _Float16* ab, int* eidx,
                                           int row0, int M, int lane) {
  int nd_end = min(row0 + 16, M);
  int ebeg = row_off[row0 < M ? row0 : M - 1];
  int eend = row_off[nd_end];
  int cnt  = eend - ebeg;
  bool fits = (cnt <= EC);
  if (fits)
    for (int i = lane; i < cnt; i += 64) eidx[i] = csr[ebeg + i];
  int g = lane >> 4, j = lane & 15;
#pragma unroll
  for (int batch = 0; batch < 4; ++batch) {
    int node = row0 + batch * 4 + g;
    int nc = (node < M) ? node : M - 1;
    int beg = row_off[nc], end = row_off[nc + 1];
    half8 acc = (half8)(_Float16)0.f;
    if (fits) {
      const int* ix = eidx + (beg - ebeg);
      int n = end - beg;
#pragma unroll 8
      for (int e = 0; e < n; ++e) {
        half8 v = *(const half8*)(X + (long)ix[e] * 128 + j * 8);
        acc += v;
      }
    } else {
#pragma unroll 8
      for (int e = beg; e < end; ++e) {
        half8 v = *(const half8*)(X + (long)csr[e] * 128 + j * 8);
        acc += v;
      }
    }
    _Float16 inv = (_Float16)(1.f / fmaxf((float)(end - beg), 1.f));
    acc *= (half8)inv;
    *(half8*)(ab + (batch * 4 + g) * 136 + j * 8) = acc;
  }
}

// ---------------- fused layer-1 + folded layer-2 GEMM ------------------------------
// h1 tile never touches global: agg -> K=256 MFMA vs Wp1 -> +b1,relu -> stage into the
// (now dead) ab LDS tile -> 8 MFMAs vs Bz -> Zl (f16) + Pr (f32). Wave-private, no barrier.
__global__ __launch_bounds__(128) void gemm1z_k(const _Float16* __restrict__ X,
                                                const int* __restrict__ row_off,
                                                const int* __restrict__ csr,
                                                const _Float16* __restrict__ Bp,
                                                const float* __restrict__ bias,
                                                const _Float16* __restrict__ Bz,
                                                const float* __restrict__ bprime,
                                                _Float16* __restrict__ Zl,
                                                float* __restrict__ Pr, int M) {
  __shared__ _Float16 abuf[2][16 * 136];
  __shared__ int      ebuf[2][EC];
  int wave = threadIdx.x >> 6, lane = threadIdx.x & 63;
  _Float16* ab = abuf[wave];
  int row0 = blockIdx.x * 32 + wave * 16;
  agg_to_lds(X, row_off, csr, ab, ebuf[wave], row0, M, lane);
  int m = lane & 15, quad = lane >> 4;
  int arow = row0 + m; if (arow > M - 1) arow = M - 1;
  f32x4 acc[8];
#pragma unroll
  for (int i = 0; i < 8; ++i) acc[i] = (f32x4){0.f, 0.f, 0.f, 0.f};
#pragma unroll
  for (int kt = 0; kt < 8; ++kt) {
    half8 af = (kt < 4) ? *(const half8*)(ab + m * 136 + kt * 32 + quad * 8)
                        : *(const half8*)(X + (long)arow * 128 + (kt - 4) * 32 + quad * 8);
#pragma unroll
    for (int nt = 0; nt < 8; ++nt) {
      half8 bf = *(const half8*)(Bp + ((long)(kt * 8 + nt) * 64 + lane) * 8);
      acc[nt] = __builtin_amdgcn_mfma_f32_16x16x32_f16(af, bf, acc[nt], 0, 0, 0);
    }
  }
  // h1 tile: +b1, relu, stage into ab (agg contents are dead; same f16 rounding as
  // the old global h1 path -> bit-identical). K-loop LDS reads complete in-order.
#pragma unroll
  for (int nt = 0; nt < 8; ++nt) {
    float bv = bias[nt * 16 + m];
#pragma unroll
    for (int r = 0; r < 4; ++r)
      ab[(quad * 4 + r) * 136 + nt * 16 + m] = (_Float16)fmaxf(acc[nt][r] + bv, 0.f);
  }
  // folded layer-2: Zl = h1@W2lc, Pr = h1@W2rc + b'
  f32x4 a0 = (f32x4){0.f, 0.f, 0.f, 0.f}, a1 = a0;
#pragma unroll
  for (int kt = 0; kt < 4; ++kt) {
    half8 af = *(const half8*)(ab + m * 136 + kt * 32 + quad * 8);
    half8 b0 = *(const half8*)(Bz + ((long)(kt * 2 + 0) * 64 + lane) * 8);
    half8 b1 = *(const half8*)(Bz + ((long)(kt * 2 + 1) * 64 + lane) * 8);
    a0 = __builtin_amdgcn_mfma_f32_16x16x32_f16(af, b0, a0, 0, 0, 0);
    a1 = __builtin_amdgcn_mfma_f32_16x16x32_f16(af, b1, a1, 0, 0, 0);
  }
  float bv = bprime[m];
#pragma unroll
  for (int r = 0; r < 4; ++r) {
    int orow = row0 + quad * 4 + r;
    if (orow < M) {
      Zl[(long)orow * 16 + m] = (_Float16)a0[r];
      Pr[(long)orow * 16 + m] = a1[r] + bv;
    }
  }
}

// ---------------- final: out = mean_agg(Zl) + Pr --------------------------------
__global__ __launch_bounds__(256) void aggout_k(const _Float16* __restrict__ Zl,
                                                const float* __restrict__ Pr,
                                                const int* __restrict__ row_off,
                                                const int* __restrict__ csr,
                                                float* __restrict__ out, int M) {
  int t = blockIdx.x * 256 + threadIdx.x;
  int node = t >> 2, q = t & 3;
  if (node >= M) return;
  int beg = row_off[node], end = row_off[node + 1];
  float a0 = 0.f, a1 = 0.f, a2 = 0.f, a3 = 0.f;
#pragma unroll 8
  for (int e = beg; e < end; ++e) {
    half4 v = *(const half4*)(Zl + (long)csr[e] * 16 + q * 4);
    a0 += (float)v[0]; a1 += (float)v[1]; a2 += (float)v[2]; a3 += (float)v[3];
  }
  float inv = 1.f / fmaxf((float)(end - beg), 1.f);
  long o = (long)node * 16 + q * 4;
  const float4 pv = *(const float4*)(Pr + o);
  float4 ov;
  ov.x = a0 * inv + pv.x; ov.y = a1 * inv + pv.y;
  ov.z = a2 * inv + pv.z; ov.w = a3 * inv + pv.w;
  *(float4*)(out + o) = ov;
}

extern "C" void kernel_launch(void* const* d_in, const int* in_sizes, int n_in,
                              void* d_out, int out_size, void* d_ws, size_t ws_size,
                              hipStream_t stream) {
  const int N = in_sizes[0];
  const int E = in_sizes[1] / 2;
  const int*   entity = (const int*)d_in[0];
  const int*   e_src  = (const int*)d_in[1];
  const int*   e_dst  = e_src + E;
  const float* emb    = (const float*)d_in[2];
  const float* W1l    = (const float*)d_in[3];
  const float* b1     = (const float*)d_in[4];
  const float* W1r    = (const float*)d_in[5];
  const float* W2l    = (const float*)d_in[6];
  const float* b2     = (const float*)d_in[7];
  const float* W2r    = (const float*)d_in[8];
  const float* Wc     = (const float*)d_in[9];
  const float* bc     = (const float*)d_in[10];
  float* out = (float*)d_out;

  // workspace layout (h1 eliminated)
  char* p = (char*)d_ws;
  _Float16* x0  = (_Float16*)p; p += (size_t)N * 128 * 2;
  _Float16* Wp1 = (_Float16*)p; p += 256 * 128 * 2;
  _Float16* Wz  = (_Float16*)p; p += 128 * 32 * 2;
  float*    bpr = (float*)p;    p += 16 * 4;
  _Float16* Zl  = (_Float16*)p; p += (size_t)N * 16 * 2;
  float*    Pr  = (float*)p;    p += (size_t)N * 16 * 4;
  int* deg     = (int*)p; p += (size_t)N * 4;
  int* cur     = (int*)p; p += (size_t)N * 4;               // adjacent to deg: one memset
  int* row_off = (int*)p; p += (size_t)(N + 1) * 4;
  int* csr     = (int*)p; p += (size_t)E * 4;
  int* part    = (int*)p; p += 1024 * 4;

  const int NB = (N + 255) / 256;          // 196
  const int FB = (E + 255) / 256;          // 2344 fill blocks
  const int GB = (N * 16 + 255) / 256;     // 3125 gather blocks
  const int PER = (FB + 2) / 3 > (GB + 3) / 4 ? (FB + 2) / 3 : (GB + 3) / 4;  // 782
  const int IB = PER * 7;                  // interleaved region size

  hipMemsetAsync(deg, 0, (size_t)N * 8, stream);            // zeros deg + cur

  count_k<<<FB, 256, 0, stream>>>(e_dst, deg, E);
  deg_part_k<<<NB, 256, 0, stream>>>(deg, part, N);
  row_off_k<<<NB, 256, 0, stream>>>(deg, part, row_off, N, NB);
  // post: interleaved CSR fill + emb gather, packs at tail
  post_k<<<IB + 33, 256, 0, stream>>>(e_src, e_dst, row_off, cur, csr,
                                      entity, emb, x0, W1l, W1r, Wp1,
                                      W2l, W2r, Wc, Wz, b2, bc, bpr,
                                      N, E, FB, GB, IB);
  // fused: h1 = relu([mean_agg(x0)|x0]@Wp1+b1) -> Zl = h1@W2lc, Pr = h1@W2rc + b'
  gemm1z_k<<<(N + 31) / 32, 128, 0, stream>>>(x0, row_off, csr, Wp1, b1,
                                              Wz, bpr, Zl, Pr, N);
  // out = mean_agg(Zl) + Pr   (32 B/edge gather)
  aggout_k<<<(N * 4 + 255) / 256, 256, 0, stream>>>(Zl, Pr, row_off, csr, out, N);
}